// Round 5
// baseline (157.950 us; speedup 1.0000x reference)
//
#include <hip/hip_runtime.h>
#include <hip/hip_cooperative_groups.h>
#include <math.h>

namespace cg = cooperative_groups;

// Problem constants
#define B_   64
#define N_   256
#define DV_  2048
#define DP_  8
#define DT_  768
#define DF_  512
#define DK_  2056   // DV + DP

// Workspace layout (floats)
#define WS_WT 0        // wT[DF][B]  = 32768
#define WS_S  32768    // S[B][DP]   = 512
#define WS_C  33280    // c[B]       = 64
#define WS_V  33344    // v[B][DK]   = 131584

// Shared-memory layout (byte offsets into one 15360 B buffer)
//  Phase A: tx[4][768]   @0      (12288 B)
//           swA[4][8][4] @12288  (2048 B, float4 [wave][fq][bb])
//           spos[4][4][8]@14336  (512 B)
//  Phase B: wo[2][512]   @0      (4096 B)
//           swB[4][2][16]@4096   (2048 B, float4 [wave][row][bq])
//           sbo[512]     @6144   (2048 B)

__global__ __launch_bounds__(256) void fused(
    const float* __restrict__ visual, // [B][N][DV]
    const float* __restrict__ pos,    // [B][N][DP]
    const float* __restrict__ text,   // [B][N][DT]
    const float* __restrict__ Wt,     // [DT][DF]
    const float* __restrict__ bt,     // [DF]
    const float* __restrict__ Wo,     // [DK][DF]
    const float* __restrict__ bo,     // [DF]
    const float* __restrict__ Wa,     // [DF]
    const float* __restrict__ ba,     // [1]
    float* __restrict__ wT,           // [DF][B]
    float* __restrict__ S,            // [B][DP]
    float* __restrict__ c,            // [B]
    float* __restrict__ v,            // [B][DK]
    float* __restrict__ out)          // [B][N]
{
    __shared__ __align__(16) char smem[15360];
    const int t    = threadIdx.x;
    const int wave = t >> 6;
    const int lane = t & 63;
    cg::grid_group grid = cg::this_grid();

    // ================= Phase A: wT[f][b], S[b] =================
    {
        float*  tx   = (float*)smem;             // [4][768]
        float4* swA  = (float4*)(smem + 12288);  // [4][8][4]
        float*  spos = (float*)(smem + 14336);   // [4][4][8]

        for (int vb = blockIdx.x; vb < 256; vb += gridDim.x) {
            const int bq = vb >> 4;
            const int fg = vb & 15;

            #pragma unroll
            for (int r = 0; r < 3; ++r) {
                const int idx = t + 256 * r;          // [0,768)
                const int bb  = idx / 192;
                const int j   = idx - bb * 192;
                ((float4*)(tx + (size_t)bb * DT_))[j] =
                    ((const float4*)text)[(size_t)(bq * 4 + bb) * (N_ * DT_ / 4) + j];
            }
            if (fg == 0 && t < 128) {
                const int bb = t >> 5, l = t & 31, d = l & 7, g4 = l >> 3;
                float s = 0.f;
                for (int i = g4; i < N_; i += 4)
                    s += pos[(size_t)(bq * 4 + bb) * N_ * DP_ + i * DP_ + d];
                spos[bb * 32 + g4 * 8 + d] = s;
            }
            __syncthreads();
            if (fg == 0 && t < 32) {
                const int bb = t >> 3, d = t & 7;
                S[(bq * 4 + bb) * DP_ + d] = spos[bb * 32 + d] + spos[bb * 32 + 8 + d]
                                           + spos[bb * 32 + 16 + d] + spos[bb * 32 + 24 + d];
            }

            const int fq = t & 7;
            const int kc = t >> 3;
            const int f0 = fg * 32 + fq * 4;
            float4 a0 = make_float4(0.f, 0.f, 0.f, 0.f);
            float4 a1 = a0, a2 = a0, a3 = a0;
            const int kbase = kc * 24;
            #pragma unroll 4
            for (int j = 0; j < 24; ++j) {
                const int k = kbase + j;
                const float4 wv = *(const float4*)(Wt + (size_t)k * DF_ + f0);
                const float x0 = tx[0 * DT_ + k], x1 = tx[1 * DT_ + k];
                const float x2 = tx[2 * DT_ + k], x3 = tx[3 * DT_ + k];
                a0.x = fmaf(x0, wv.x, a0.x); a0.y = fmaf(x0, wv.y, a0.y);
                a0.z = fmaf(x0, wv.z, a0.z); a0.w = fmaf(x0, wv.w, a0.w);
                a1.x = fmaf(x1, wv.x, a1.x); a1.y = fmaf(x1, wv.y, a1.y);
                a1.z = fmaf(x1, wv.z, a1.z); a1.w = fmaf(x1, wv.w, a1.w);
                a2.x = fmaf(x2, wv.x, a2.x); a2.y = fmaf(x2, wv.y, a2.y);
                a2.z = fmaf(x2, wv.z, a2.z); a2.w = fmaf(x2, wv.w, a2.w);
                a3.x = fmaf(x3, wv.x, a3.x); a3.y = fmaf(x3, wv.y, a3.y);
                a3.z = fmaf(x3, wv.z, a3.z); a3.w = fmaf(x3, wv.w, a3.w);
            }
            // butterfly over kc-in-wave (lane bits 3,4,5)
            #pragma unroll
            for (int m = 8; m <= 32; m <<= 1) {
                a0.x += __shfl_xor(a0.x, m, 64); a0.y += __shfl_xor(a0.y, m, 64);
                a0.z += __shfl_xor(a0.z, m, 64); a0.w += __shfl_xor(a0.w, m, 64);
                a1.x += __shfl_xor(a1.x, m, 64); a1.y += __shfl_xor(a1.y, m, 64);
                a1.z += __shfl_xor(a1.z, m, 64); a1.w += __shfl_xor(a1.w, m, 64);
                a2.x += __shfl_xor(a2.x, m, 64); a2.y += __shfl_xor(a2.y, m, 64);
                a2.z += __shfl_xor(a2.z, m, 64); a2.w += __shfl_xor(a2.w, m, 64);
                a3.x += __shfl_xor(a3.x, m, 64); a3.y += __shfl_xor(a3.y, m, 64);
                a3.z += __shfl_xor(a3.z, m, 64); a3.w += __shfl_xor(a3.w, m, 64);
            }
            if (lane < 8) {   // lane == fq here
                swA[wave * 32 + lane * 4 + 0] = a0;
                swA[wave * 32 + lane * 4 + 1] = a1;
                swA[wave * 32 + lane * 4 + 2] = a2;
                swA[wave * 32 + lane * 4 + 3] = a3;
            }
            __syncthreads();
            if (t < 32) {
                const int fq2 = t & 7, bb = t >> 3;
                float4 s = swA[fq2 * 4 + bb];
                #pragma unroll
                for (int w = 1; w < 4; ++w) {
                    const float4 p = swA[w * 32 + fq2 * 4 + bb];
                    s.x += p.x; s.y += p.y; s.z += p.z; s.w += p.w;
                }
                const float sv[4] = {s.x, s.y, s.z, s.w};
                const int b = bq * 4 + bb;
                #pragma unroll
                for (int cc = 0; cc < 4; ++cc) {
                    const int f = fg * 32 + fq2 * 4 + cc;
                    const float z = sv[cc] + bt[f];
                    const float ge = 0.5f * z * (1.f + erff(z * 0.70710678118654752f));
                    wT[(size_t)f * B_ + b] = ge * Wa[f];
                }
            }
            __syncthreads();
        }
    }

    __threadfence();
    grid.sync();

    // ================= Phase B: v[b][k], c[b] =================
    {
        float*  wo  = (float*)smem;             // [2][512]
        float4* swB = (float4*)(smem + 4096);   // [4][2][16]
        float*  sbo = (float*)(smem + 6144);    // [512]

        for (int vb = blockIdx.x; vb < 1029; vb += gridDim.x) {
            if (vb < 1028) {
                const int k0 = vb * 2;
                ((float4*)wo)[t] = ((const float4*)(Wo + (size_t)k0 * DF_))[t];
                __syncthreads();

                const int bq = t & 15;
                const int fgi = t >> 4;
                float4 acc0 = make_float4(0.f, 0.f, 0.f, 0.f);
                float4 acc1 = acc0;
                const int fbase = fgi * 32;
                #pragma unroll 4
                for (int j = 0; j < 32; ++j) {
                    const int f = fbase + j;
                    const float4 wv = *(const float4*)(wT + (size_t)f * B_ + 4 * bq);
                    const float s0 = wo[f], s1 = wo[DF_ + f];
                    acc0.x = fmaf(s0, wv.x, acc0.x); acc0.y = fmaf(s0, wv.y, acc0.y);
                    acc0.z = fmaf(s0, wv.z, acc0.z); acc0.w = fmaf(s0, wv.w, acc0.w);
                    acc1.x = fmaf(s1, wv.x, acc1.x); acc1.y = fmaf(s1, wv.y, acc1.y);
                    acc1.z = fmaf(s1, wv.z, acc1.z); acc1.w = fmaf(s1, wv.w, acc1.w);
                }
                // butterfly over fgi-in-wave (lane bits 4,5)
                #pragma unroll
                for (int m = 16; m <= 32; m <<= 1) {
                    acc0.x += __shfl_xor(acc0.x, m, 64); acc0.y += __shfl_xor(acc0.y, m, 64);
                    acc0.z += __shfl_xor(acc0.z, m, 64); acc0.w += __shfl_xor(acc0.w, m, 64);
                    acc1.x += __shfl_xor(acc1.x, m, 64); acc1.y += __shfl_xor(acc1.y, m, 64);
                    acc1.z += __shfl_xor(acc1.z, m, 64); acc1.w += __shfl_xor(acc1.w, m, 64);
                }
                if (lane < 16) {   // lane == bq here
                    swB[wave * 32 + lane]      = acc0;
                    swB[wave * 32 + 16 + lane] = acc1;
                }
                __syncthreads();
                if (t < 32) {
                    const int row = t >> 4, bq2 = t & 15;
                    float4 s = swB[row * 16 + bq2];
                    #pragma unroll
                    for (int w = 1; w < 4; ++w) {
                        const float4 p = swB[w * 32 + row * 16 + bq2];
                        s.x += p.x; s.y += p.y; s.z += p.z; s.w += p.w;
                    }
                    const float sv[4] = {s.x, s.y, s.z, s.w};
                    #pragma unroll
                    for (int cc = 0; cc < 4; ++cc)
                        v[(size_t)(4 * bq2 + cc) * DK_ + k0 + row] = sv[cc];
                }
                __syncthreads();
            } else {
                // c[b] = ba + sum_f bo[f]*w[b,f]
                for (int k = t; k < DF_; k += 256) sbo[k] = bo[k];
                __syncthreads();
                const int bq = t & 15;
                const int fh = t >> 4;
                float4 acc = make_float4(0.f, 0.f, 0.f, 0.f);
                for (int j = 0; j < 32; ++j) {
                    const int f = fh * 32 + j;
                    const float s = sbo[f];
                    const float4 wv = *(const float4*)(wT + (size_t)f * B_ + 4 * bq);
                    acc.x = fmaf(s, wv.x, acc.x); acc.y = fmaf(s, wv.y, acc.y);
                    acc.z = fmaf(s, wv.z, acc.z); acc.w = fmaf(s, wv.w, acc.w);
                }
                #pragma unroll
                for (int m = 16; m <= 32; m <<= 1) {
                    acc.x += __shfl_xor(acc.x, m, 64); acc.y += __shfl_xor(acc.y, m, 64);
                    acc.z += __shfl_xor(acc.z, m, 64); acc.w += __shfl_xor(acc.w, m, 64);
                }
                if (lane < 16) swB[wave * 32 + lane] = acc;
                __syncthreads();
                if (t < 16) {
                    float4 s = swB[t];
                    #pragma unroll
                    for (int w = 1; w < 4; ++w) {
                        const float4 p = swB[w * 32 + t];
                        s.x += p.x; s.y += p.y; s.z += p.z; s.w += p.w;
                    }
                    const float sv[4] = {s.x, s.y, s.z, s.w};
                    #pragma unroll
                    for (int cc = 0; cc < 4; ++cc)
                        c[4 * t + cc] = sv[cc] + ba[0];
                }
                __syncthreads();
            }
        }
    }

    __threadfence();
    grid.sync();

    // ================= Phase C: out (HBM-bound stream) =================
    for (int vb = blockIdx.x; vb < 2048; vb += gridDim.x) {
        const int b  = vb >> 5;
        const int r0 = ((vb & 31) << 3) + wave * 2;

        const float4* vb4 = (const float4*)(v + (size_t)b * DK_);
        const float4* v0  = (const float4*)(visual + ((size_t)b * N_ + r0) * DV_);

        float a0 = 0.f, a1 = 0.f;
        #pragma unroll
        for (int j = 0; j < 8; ++j) {
            const int idx = lane + 64 * j;
            const float4 wv = vb4[idx];
            const float4 x0 = v0[idx];
            const float4 x1 = v0[idx + 512];
            a0 = fmaf(x0.x, wv.x, a0); a0 = fmaf(x0.y, wv.y, a0);
            a0 = fmaf(x0.z, wv.z, a0); a0 = fmaf(x0.w, wv.w, a0);
            a1 = fmaf(x1.x, wv.x, a1); a1 = fmaf(x1.y, wv.y, a1);
            a1 = fmaf(x1.z, wv.z, a1); a1 = fmaf(x1.w, wv.w, a1);
        }
        #pragma unroll
        for (int off = 1; off < 64; off <<= 1) {
            a0 += __shfl_xor(a0, off, 64);
            a1 += __shfl_xor(a1, off, 64);
        }

        if (lane < 2) {
            const float accq = (lane == 0) ? a0 : a1;
            const int i = r0 + lane;
            const float* v2 = v + (size_t)b * DK_ + DV_;
            const float* pr = pos + ((size_t)b * N_ + i) * DP_;
            const float* Sb = S + b * DP_;
            float pd = 0.f, sd = 0.f;
            #pragma unroll
            for (int d = 0; d < DP_; ++d) {
                pd = fmaf(pr[d], v2[d], pd);
                sd = fmaf(Sb[d], v2[d], sd);
            }
            out[(size_t)b * N_ + i] = accq + 257.f * pd - sd + c[b];
        }
    }
}

// ---------------------------------------------------------------------------
extern "C" void kernel_launch(void* const* d_in, const int* in_sizes, int n_in,
                              void* d_out, int out_size, void* d_ws, size_t ws_size,
                              hipStream_t stream) {
    const float* visual   = (const float*)d_in[0];
    const float* position = (const float*)d_in[1];
    const float* text     = (const float*)d_in[2];
    const float* Wt       = (const float*)d_in[3];
    const float* bt       = (const float*)d_in[4];
    const float* Wo       = (const float*)d_in[5];
    const float* bo       = (const float*)d_in[6];
    const float* Wa       = (const float*)d_in[7];
    const float* ba       = (const float*)d_in[8];
    float* out = (float*)d_out;

    float* ws = (float*)d_ws;
    float* wT = ws + WS_WT;
    float* S  = ws + WS_S;
    float* c  = ws + WS_C;
    float* v  = ws + WS_V;

    int maxB = 0;
    hipOccupancyMaxActiveBlocksPerMultiprocessor(&maxB, fused, 256, 0);
    if (maxB < 1) maxB = 1;
    int grid = maxB * 256;           // 256 CUs on MI355X
    if (grid > 2048) grid = 2048;

    void* args[] = {
        (void*)&visual, (void*)&position, (void*)&text, (void*)&Wt, (void*)&bt,
        (void*)&Wo, (void*)&bo, (void*)&Wa, (void*)&ba,
        (void*)&wT, (void*)&S, (void*)&c, (void*)&v, (void*)&out
    };
    hipLaunchCooperativeKernel((void*)fused, dim3(grid), dim3(256), args, 0, stream);
}